// Round 11
// baseline (416.748 us; speedup 1.0000x reference)
//
#include <hip/hip_runtime.h>

// R11: (a) SL∘OUT algebraic fold: Wc = Wsl @ Wout precomputed in prep2 with
// scales baked -> OUT stages and ns/nv LDS round-trips deleted. (b) LDS
// compaction: one [16][260] arena/wave (phase-overlapped regions) -> 33,280
// B/block -> 4 blocks/CU (16 waves/CU). launch_bounds(256,4) caps VGPR 128.

typedef short  bf16x8 __attribute__((ext_vector_type(8)));
typedef float  f32x4  __attribute__((ext_vector_type(4)));

#define FENCE() asm volatile("" ::: "memory")

constexpr float BETA  = 1.6791767f;
constexpr float RS128 = 0.088388347648318447f;
constexpr float RS64  = 0.125f;
constexpr float RS32  = 0.176776695296636881f;
constexpr float RSQ3  = 0.577350269189625842f;

enum : int {
  O_nm1 = 0,      O_nm2 = 4096,   O_nm3 = 8192,
  O_em1 = 20480,  O_em2 = 24576,  O_em3 = 28672,
  O_nss = 40960,  O_nsv = 49152,  O_nvv = 53248,  O_nvs = 57344,
  O_ess = 59392,  O_esv = 63488,  O_evv = 65536,  O_evs = 67584,
  O_cns = 68608,  O_cnv = 76800,  O_ces = 78848,  O_cev = 87040,  // combined
  W_TOTAL = 89088
};

// arena column bases (per-wave [16][260] ushort)
enum : int { ST = 260, H0n = 0, H0e = 64, H1n = 128, H1e = 192, MSP = 0, MV = 128 };

struct Ptrs {
  const float *src, *dst, *ef, *env, *scal;
  const ushort* wf;
  float *out;
};

struct PrepArgs {
  const float* src[14];
  int K[14], N[14], ofs[14];
  ushort* dst;
};
struct Prep2Args {
  const float* A[4]; const float* B[4];
  int K[4], N[4], inner[4], ofs[4];
  float scale[4];
  ushort* dst;
};

__device__ __forceinline__ ushort f2b(float x) {
  union { float f; unsigned u; } v; v.f = x;
  unsigned r = v.u + 0x7fffu + ((v.u >> 16) & 1u);
  return (ushort)(r >> 16);
}
__device__ __forceinline__ unsigned pk2(float a, float b) {
  unsigned r;
  asm("v_cvt_pk_bf16_f32 %0, %1, %2" : "=v"(r) : "v"(a), "v"(b));
  return r;
}
__device__ __forceinline__ float plo(unsigned p) {
  union { unsigned u; float f; } v; v.u = p << 16; return v.f;
}
__device__ __forceinline__ float phi(unsigned p) {
  union { unsigned u; float f; } v; v.u = p & 0xffff0000u; return v.f;
}

__global__ __launch_bounds__(256) void prep_kernel(PrepArgs A) {
  const int mat = blockIdx.x;
  const float* __restrict__ src = A.src[mat];
  const int K = A.K[mat], N = A.N[mat], KS = K >> 5;
  ushort* dst = A.dst + A.ofs[mat];
  const int total = (N * K) >> 3;
  for (int gi = threadIdx.x; gi < total; gi += 256) {
    int t = gi / (64 * KS), r = gi - t * 64 * KS;
    int ks = r >> 6, lane = r & 63;
    int cc = lane & 15, gg = lane >> 4;
    int n = t * 16 + cc, k0 = ks * 32 + gg * 8;
    ushort v[8];
#pragma unroll
    for (int j = 0; j < 8; ++j) v[j] = f2b(src[(size_t)(k0 + j) * N + n]);
    *(uint4*)(dst + (size_t)gi * 8) = *(const uint4*)v;
  }
}

// combined W = (A @ B) * scale, packed directly to fragment-major
__global__ __launch_bounds__(256) void prep2_kernel(Prep2Args Z) {
  const int m = blockIdx.x;
  const float* __restrict__ A = Z.A[m];
  const float* __restrict__ B = Z.B[m];
  const int K = Z.K[m], N = Z.N[m], I = Z.inner[m], KS = K >> 5;
  const float sc = Z.scale[m];
  ushort* dst = Z.dst + Z.ofs[m];
  const int total = (N * K) >> 3;
  for (int gi = threadIdx.x; gi < total; gi += 256) {
    int t = gi / (64 * KS), r = gi - t * 64 * KS;
    int ks = r >> 6, lane = r & 63;
    int cc = lane & 15, gg = lane >> 4;
    int n = t * 16 + cc, k0 = ks * 32 + gg * 8;
    ushort v[8];
    for (int j = 0; j < 8; ++j) {
      float acc = 0.f;
      for (int u = 0; u < I; ++u)
        acc += A[(size_t)(k0 + j) * I + u] * B[(size_t)u * N + n];
      v[j] = f2b(acc * sc);
    }
    *(uint4*)(dst + (size_t)gi * 8) = *(const uint4*)v;
  }
}

template<int N>
__device__ __forceinline__ void lda(const ushort* __restrict__ wb, unsigned lofs, bf16x8* a) {
#pragma unroll
  for (int i = 0; i < N; ++i) a[i] = *(const bf16x8*)(wb + i * 512 + lofs);
}
template<int T, int KS>
__device__ __forceinline__ void mfm(const bf16x8* a, const bf16x8* bf, f32x4* out) {
#pragma unroll
  for (int t = 0; t < T; ++t) {
    f32x4 acc = (f32x4){0, 0, 0, 0};
#pragma unroll
    for (int ks = 0; ks < KS; ++ks)
      acc = __builtin_amdgcn_mfma_f32_16x16x32_bf16(a[t * KS + ks], bf[ks], acc, 0, 0, 0);
    out[t] = acc;
  }
}
template<int T, int KS>
__device__ __forceinline__ void mfmacc(const bf16x8* a, const bf16x8* bf, f32x4* out) {
#pragma unroll
  for (int t = 0; t < T; ++t)
#pragma unroll
    for (int ks = 0; ks < KS; ++ks)
      out[t] = __builtin_amdgcn_mfma_f32_16x16x32_bf16(a[t * KS + ks], bf[ks], out[t], 0, 0, 0);
}

__device__ __forceinline__ void put2(ushort* b, int cg, int col, const f32x4& d) {
  uint2 p; p.x = pk2(d[0], d[1]); p.y = pk2(d[2], d[3]);
  *(uint2*)(b + cg + col) = p;
}
__device__ __forceinline__ bf16x8 getf(const ushort* b, int cg, int col, int g) {
  return *(const bf16x8*)(b + cg + col + 8 * g);
}
__device__ __forceinline__ bf16x8 ldf8(const float* __restrict__ p) {
  float4 a = *(const float4*)p, b4 = *(const float4*)(p + 4);
  union { unsigned u[4]; bf16x8 v; } r;
  r.u[0] = pk2(a.x, a.y); r.u[1] = pk2(a.z, a.w);
  r.u[2] = pk2(b4.x, b4.y); r.u[3] = pk2(b4.z, b4.w);
  return r.v;
}
__device__ __forceinline__ f32x4 silu4(const f32x4& d) {
  f32x4 o;
#pragma unroll
  for (int r = 0; r < 4; ++r) { float z = d[r] * 0.125f; o[r] = BETA * z / (1.f + __expf(-z)); }
  return o;
}
__device__ __forceinline__ void vecwin(const float* __restrict__ p,
                                       float y0, float y1, float y2,
                                       bf16x8& dotf, bf16x8* xvf) {
  float v[24];
#pragma unroll
  for (int q = 0; q < 6; ++q) *(float4*)&v[4 * q] = *(const float4*)(p + 4 * q);
  float dj[8];
#pragma unroll
  for (int j = 0; j < 8; ++j)
    dj[j] = (v[3 * j] * y0 + v[3 * j + 1] * y1 + v[3 * j + 2] * y2) * RSQ3;
  union { unsigned u[4]; bf16x8 w; } t;
#pragma unroll
  for (int q = 0; q < 4; ++q) t.u[q] = pk2(dj[2 * q], dj[2 * q + 1]);
  dotf = t.w;
#pragma unroll
  for (int i = 0; i < 3; ++i) {
#pragma unroll
    for (int q = 0; q < 4; ++q) t.u[q] = pk2(v[6 * q + i], v[6 * q + 3 + i]);
    xvf[i] = t.w;
  }
}

// MLP3 -> 12 packed w-tiles, chunked 3-tile rotation
__device__ __forceinline__ void mlp3(const ushort* __restrict__ wb, unsigned lofs,
                                     const bf16x8* h2, uint2* Wp) {
  bf16x8 aa[6], ab[6];
  lda<6>(wb, lofs, aa);
  lda<6>(wb + 6 * 512, lofs, ab);
  f32x4 dw[3];
  mfm<3, 2>(aa, h2, dw);
  lda<6>(wb + 12 * 512, lofs, aa);
#pragma unroll
  for (int t = 0; t < 3; ++t) { Wp[t].x = pk2(dw[t][0]*0.125f, dw[t][1]*0.125f); Wp[t].y = pk2(dw[t][2]*0.125f, dw[t][3]*0.125f); }
  mfm<3, 2>(ab, h2, dw);
  lda<6>(wb + 18 * 512, lofs, ab);
#pragma unroll
  for (int t = 0; t < 3; ++t) { Wp[3+t].x = pk2(dw[t][0]*0.125f, dw[t][1]*0.125f); Wp[3+t].y = pk2(dw[t][2]*0.125f, dw[t][3]*0.125f); }
  mfm<3, 2>(aa, h2, dw);
#pragma unroll
  for (int t = 0; t < 3; ++t) { Wp[6+t].x = pk2(dw[t][0]*0.125f, dw[t][1]*0.125f); Wp[6+t].y = pk2(dw[t][2]*0.125f, dw[t][3]*0.125f); }
  mfm<3, 2>(ab, h2, dw);
#pragma unroll
  for (int t = 0; t < 3; ++t) { Wp[9+t].x = pk2(dw[t][0]*0.125f, dw[t][1]*0.125f); Wp[9+t].y = pk2(dw[t][2]*0.125f, dw[t][3]*0.125f); }
}

// TP + folded SL for one path. ACC=false: overwrite os/ov; true: accumulate.
template<bool ED, bool ACC>
__device__ __forceinline__ void tp_sl(
    const ushort* __restrict__ WF, ushort* bA, int cg, int g, unsigned lofs,
    const bf16x8* xsf, const bf16x8* dotf, const bf16x8* xvi,
    const uint2* Wp, float ys, float yv0, float yv1, float yv2,
    f32x4* os, f32x4 (*ov)[2]) {
  constexpr int KA = ED ? 2 : 4;
  constexpr int KB = ED ? 1 : 2;
  const float SA = ED ? RS64 : RS128;
  const float SB = ED ? RS32 : RS64;

  // s_a -> MSP[0..63]
  {
    bf16x8 a[4 * KA]; f32x4 d[4];
    lda<4 * KA>(WF + (ED ? O_ess : O_nss), lofs, a);
    mfm<4, KA>(a, xsf, d);
#pragma unroll
    for (int t = 0; t < 4; ++t) {
      f32x4 m;
      m[0] = d[t][0]*ys*SA*plo(Wp[t].x); m[1] = d[t][1]*ys*SA*phi(Wp[t].x);
      m[2] = d[t][2]*ys*SA*plo(Wp[t].y); m[3] = d[t][3]*ys*SA*phi(Wp[t].y);
      put2(bA, cg, MSP + 16 * t + 4 * g, m);
    }
  }
  // s_b -> MSP[64..127]
  {
    bf16x8 a[4 * KB]; f32x4 d[4];
    lda<4 * KB>(WF + (ED ? O_evv : O_nvv), lofs, a);
    mfm<4, KB>(a, dotf, d);
#pragma unroll
    for (int t = 0; t < 4; ++t) {
      f32x4 m;
      m[0] = d[t][0]*SB*plo(Wp[4+t].x); m[1] = d[t][1]*SB*phi(Wp[4+t].x);
      m[2] = d[t][2]*SB*plo(Wp[4+t].y); m[3] = d[t][3]*SB*phi(Wp[4+t].y);
      put2(bA, cg, MSP + 64 + 16 * t + 4 * g, m);
    }
  }
  FENCE();
  // read mpf early; prefetch folded-SL weights
  bf16x8 mpf[4];
#pragma unroll
  for (int ks = 0; ks < 4; ++ks) mpf[ks] = getf(bA, cg, MSP + 32 * ks, g);
  bf16x8 acs[16];
  lda<16>(WF + (ED ? O_ces : O_cns), lofs, acs);

  // v_a shared tiles + per-i v_b -> MV scratch -> folded SL-v accumulate
  f32x4 ga[2];
  {
    bf16x8 a[2 * KA];
    lda<2 * KA>(WF + (ED ? O_esv : O_nsv), lofs, a);
    mfm<2, KA>(a, xsf, ga);
  }
  bf16x8 avs[2 * KB];
  lda<2 * KB>(WF + (ED ? O_evs : O_nvs), lofs, avs);
  bf16x8 acv[4];
  lda<4>(WF + (ED ? O_cev : O_cnv), lofs, acv);
#pragma unroll
  for (int i = 0; i < 3; ++i) {
    f32x4 db[2];
    mfm<2, KB>(avs, xvi + i * KB, db);
    float yvi = (i == 0) ? yv0 : ((i == 1) ? yv1 : yv2);
#pragma unroll
    for (int t = 0; t < 2; ++t) {
      f32x4 m;
      m[0] = ga[t][0]*SA*yvi*plo(Wp[8+t].x); m[1] = ga[t][1]*SA*yvi*phi(Wp[8+t].x);
      m[2] = ga[t][2]*SA*yvi*plo(Wp[8+t].y); m[3] = ga[t][3]*SA*yvi*phi(Wp[8+t].y);
      put2(bA, cg, MV + 16 * t + 4 * g, m);
    }
#pragma unroll
    for (int t = 0; t < 2; ++t) {
      f32x4 m;
      m[0] = db[t][0]*ys*SB*plo(Wp[10+t].x); m[1] = db[t][1]*ys*SB*phi(Wp[10+t].x);
      m[2] = db[t][2]*ys*SB*plo(Wp[10+t].y); m[3] = db[t][3]*ys*SB*phi(Wp[10+t].y);
      put2(bA, cg, MV + 32 + 16 * t + 4 * g, m);
    }
    FENCE();
    bf16x8 mvf[2] = { getf(bA, cg, MV, g), getf(bA, cg, MV + 32, g) };
    if (ACC) mfmacc<2, 2>(acv, mvf, ov[i]);
    else     mfm<2, 2>(acv, mvf, ov[i]);
    FENCE();   // ov read-back done before next i overwrites MV
  }
  // folded SL-s accumulate (mpf long since read)
  if (ACC) mfmacc<4, 4>(acs, mpf, os);
  else     mfm<4, 4>(acs, mpf, os);
}

__global__ __launch_bounds__(256, 4) void mp_kernel(Ptrs P) {
  const int tid  = threadIdx.x;
  const int lane = tid & 63, wid = tid >> 6;
  const int c    = lane & 15, g  = lane >> 4;
  const unsigned lofs = lane * 8;
  const int cg   = c * ST;
  const int e    = (blockIdx.x * 4 + wid) * 16 + c;
  const ushort* __restrict__ WF = P.wf;

  __shared__ ushort sb[4][16][ST];
  ushort* bA = &sb[wid][0][0];

  const float* __restrict__ rs = P.src + (size_t)e * 160;
  const float* __restrict__ rd = P.dst + (size_t)e * 160;
  const float* __restrict__ re = P.ef  + (size_t)e * 160;
  const float* __restrict__ rq = P.scal + (size_t)e * 64;

  bf16x8 a1n[8], a1e[8];
  lda<8>(WF + O_nm1, lofs, a1n);
  lda<8>(WF + O_em1, lofs, a1e);

  float4 ev = *(const float4*)(P.env + (size_t)e * 4);
  const float ys = ev.x, yv0 = ev.y, yv1 = ev.z, yv2 = ev.w;
  bf16x8 sc[2];
  sc[0] = ldf8(rq + 8 * g);
  sc[1] = ldf8(rq + 32 + 8 * g);

  // ---- MLP1 (node+edge interleaved) ----
  {
    f32x4 dn[4], de[4];
    mfm<4, 2>(a1n, sc, dn); mfm<4, 2>(a1e, sc, de);
#pragma unroll
    for (int t = 0; t < 4; ++t) put2(bA, cg, H0n + 16 * t + 4 * g, silu4(dn[t]));
#pragma unroll
    for (int t = 0; t < 4; ++t) put2(bA, cg, H0e + 16 * t + 4 * g, silu4(de[t]));
  }
  FENCE();

  // ---- MLP2 + node TP input streams ----
  bf16x8 a2n[8], a2e[8];
  lda<8>(WF + O_nm2, lofs, a2n);
  lda<8>(WF + O_em2, lofs, a2e);
  bf16x8 xsf_n[4];
  xsf_n[0] = ldf8(rs + 8 * g);  xsf_n[1] = ldf8(rs + 32 + 8 * g);
  xsf_n[2] = ldf8(rd + 8 * g);  xsf_n[3] = ldf8(rd + 32 + 8 * g);
  bf16x8 dot_n[2], xv_n[6];
  {
    bf16x8 tmp[3];
    vecwin(rs + 64 + 24 * g, yv0, yv1, yv2, dot_n[0], tmp);
    xv_n[0] = tmp[0]; xv_n[2] = tmp[1]; xv_n[4] = tmp[2];
    vecwin(rd + 64 + 24 * g, yv0, yv1, yv2, dot_n[1], tmp);
    xv_n[1] = tmp[0]; xv_n[3] = tmp[1]; xv_n[5] = tmp[2];
  }
  {
    bf16x8 hn[2] = { getf(bA, cg, H0n, g), getf(bA, cg, H0n + 32, g) };
    bf16x8 he[2] = { getf(bA, cg, H0e, g), getf(bA, cg, H0e + 32, g) };
    f32x4 dn[4], de[4];
    mfm<4, 2>(a2n, hn, dn); mfm<4, 2>(a2e, he, de);
#pragma unroll
    for (int t = 0; t < 4; ++t) put2(bA, cg, H1n + 16 * t + 4 * g, silu4(dn[t]));
#pragma unroll
    for (int t = 0; t < 4; ++t) put2(bA, cg, H1e + 16 * t + 4 * g, silu4(de[t]));
  }
  FENCE();

  // ---- node MLP3 ----
  uint2 Wpn[12];
  {
    bf16x8 h2n[2] = { getf(bA, cg, H1n, g), getf(bA, cg, H1n + 32, g) };
    mlp3(WF + O_nm3, lofs, h2n, Wpn);
  }
  FENCE();   // H1n read complete before node TP overwrites MSP/MV

  // ---- node TP + folded SL (overwrite os/ov) ----
  f32x4 os[4]; f32x4 ov[3][2];
  tp_sl<false, false>(WF, bA, cg, g, lofs, xsf_n, dot_n, xv_n, Wpn, ys, yv0, yv1, yv2, os, ov);

  // ---- edge MLP3 (H1e still live at cols 192..255) + edge TP inputs ----
  bf16x8 xsf_e[2], dot_e[1], xv_e[3];
  xsf_e[0] = ldf8(re + 8 * g); xsf_e[1] = ldf8(re + 32 + 8 * g);
  {
    bf16x8 tmp[3];
    vecwin(re + 64 + 24 * g, yv0, yv1, yv2, dot_e[0], tmp);
    xv_e[0] = tmp[0]; xv_e[1] = tmp[1]; xv_e[2] = tmp[2];
  }
  uint2 Wpe[12];
  {
    bf16x8 h2e[2] = { getf(bA, cg, H1e, g), getf(bA, cg, H1e + 32, g) };
    mlp3(WF + O_em3, lofs, h2e, Wpe);
  }
  FENCE();

  // ---- edge TP + folded SL (accumulate) ----
  tp_sl<true, true>(WF, bA, cg, g, lofs, xsf_e, dot_e, xv_e, Wpe, ys, yv0, yv1, yv2, os, ov);

  // ---- store (scales baked into combined weights) ----
  float* __restrict__ po = P.out + (size_t)e * 160;
#pragma unroll
  for (int t = 0; t < 4; ++t) {
    float4 o = { os[t][0], os[t][1], os[t][2], os[t][3] };
    *(float4*)(po + 16 * t + 4 * g) = o;
  }
#pragma unroll
  for (int t = 0; t < 2; ++t) {
    float vv[12];
#pragma unroll
    for (int r = 0; r < 4; ++r)
#pragma unroll
      for (int i = 0; i < 3; ++i) vv[3 * r + i] = ov[i][t][r];
    *(float4*)(po + 64 + 48 * t + 12 * g)     = *(float4*)&vv[0];
    *(float4*)(po + 64 + 48 * t + 12 * g + 4) = *(float4*)&vv[4];
    *(float4*)(po + 64 + 48 * t + 12 * g + 8) = *(float4*)&vv[8];
  }
}

extern "C" void kernel_launch(void* const* d_in, const int* in_sizes, int n_in,
                              void* d_out, int out_size, void* d_ws, size_t ws_size,
                              hipStream_t stream) {
  PrepArgs A;
  const int src_idx[14] = {21,22,23, 24,25,26, 5,7,6,8, 9,11,10,12};
  const int Ks[14] = {64,64,64, 64,64,64, 128,128,64,64, 64,64,32,32};
  const int Ns[14] = {64,64,192, 64,64,192, 64,32,64,32, 64,32,64,32};
  const int Os[14] = {O_nm1,O_nm2,O_nm3, O_em1,O_em2,O_em3,
                      O_nss,O_nsv,O_nvv,O_nvs, O_ess,O_esv,O_evv,O_evs};
  for (int i = 0; i < 14; ++i) {
    A.src[i] = (const float*)d_in[src_idx[i]];
    A.K[i] = Ks[i]; A.N[i] = Ns[i]; A.ofs[i] = Os[i];
  }
  A.dst = (ushort*)d_ws;
  prep_kernel<<<dim3(14), dim3(256), 0, stream>>>(A);

  Prep2Args Z;
  // 0: node-s = Wns_s @ Wno_s ; 1: node-v = Wns_v @ Wno_v ; 2/3: edge
  Z.A[0] = (const float*)d_in[13]; Z.B[0] = (const float*)d_in[17];
  Z.K[0] = 128; Z.N[0] = 64; Z.inner[0] = 64; Z.ofs[0] = O_cns; Z.scale[0] = RS128 * RS64;
  Z.A[1] = (const float*)d_in[14]; Z.B[1] = (const float*)d_in[18];
  Z.K[1] = 64;  Z.N[1] = 32; Z.inner[1] = 32; Z.ofs[1] = O_cnv; Z.scale[1] = RS64 * RS32;
  Z.A[2] = (const float*)d_in[15]; Z.B[2] = (const float*)d_in[19];
  Z.K[2] = 128; Z.N[2] = 64; Z.inner[2] = 64; Z.ofs[2] = O_ces; Z.scale[2] = RS128 * RS64;
  Z.A[3] = (const float*)d_in[16]; Z.B[3] = (const float*)d_in[20];
  Z.K[3] = 64;  Z.N[3] = 32; Z.inner[3] = 32; Z.ofs[3] = O_cev; Z.scale[3] = RS64 * RS32;
  Z.dst = (ushort*)d_ws;
  prep2_kernel<<<dim3(4), dim3(256), 0, stream>>>(Z);

  Ptrs P;
  P.src  = (const float*)d_in[0];
  P.dst  = (const float*)d_in[1];
  P.ef   = (const float*)d_in[2];
  P.env  = (const float*)d_in[3];
  P.scal = (const float*)d_in[4];
  P.wf   = (const ushort*)d_ws;
  P.out  = (float*)d_out;

  const int E = in_sizes[0] / 160;  // 131072
  mp_kernel<<<dim3(E / 64), dim3(256), 0, stream>>>(P);
}

// Round 12
// 306.559 us; speedup vs baseline: 1.3594x; 1.3594x over previous
//
#include <hip/hip_runtime.h>

// R12: R11 (SL∘OUT fold + compact 33KB LDS arena) with __launch_bounds__(256,2)
// restored -> VGPR cap 256, no scratch spill (R11's (256,4) clamped to 64 VGPR
// and spilled ~490MB). At ~128 VGPR the HW still fits 4 waves/SIMD; LDS allows
// 4 blocks/CU -> target 16 waves/CU without spill.

typedef short  bf16x8 __attribute__((ext_vector_type(8)));
typedef float  f32x4  __attribute__((ext_vector_type(4)));

#define FENCE() asm volatile("" ::: "memory")

constexpr float BETA  = 1.6791767f;
constexpr float RS128 = 0.088388347648318447f;
constexpr float RS64  = 0.125f;
constexpr float RS32  = 0.176776695296636881f;
constexpr float RSQ3  = 0.577350269189625842f;

enum : int {
  O_nm1 = 0,      O_nm2 = 4096,   O_nm3 = 8192,
  O_em1 = 20480,  O_em2 = 24576,  O_em3 = 28672,
  O_nss = 40960,  O_nsv = 49152,  O_nvv = 53248,  O_nvs = 57344,
  O_ess = 59392,  O_esv = 63488,  O_evv = 65536,  O_evs = 67584,
  O_cns = 68608,  O_cnv = 76800,  O_ces = 78848,  O_cev = 87040,  // combined
  W_TOTAL = 89088
};

// arena column bases (per-wave [16][260] ushort)
enum : int { ST = 260, H0n = 0, H0e = 64, H1n = 128, H1e = 192, MSP = 0, MV = 128 };

struct Ptrs {
  const float *src, *dst, *ef, *env, *scal;
  const ushort* wf;
  float *out;
};

struct PrepArgs {
  const float* src[14];
  int K[14], N[14], ofs[14];
  ushort* dst;
};
struct Prep2Args {
  const float* A[4]; const float* B[4];
  int K[4], N[4], inner[4], ofs[4];
  float scale[4];
  ushort* dst;
};

__device__ __forceinline__ ushort f2b(float x) {
  union { float f; unsigned u; } v; v.f = x;
  unsigned r = v.u + 0x7fffu + ((v.u >> 16) & 1u);
  return (ushort)(r >> 16);
}
__device__ __forceinline__ unsigned pk2(float a, float b) {
  unsigned r;
  asm("v_cvt_pk_bf16_f32 %0, %1, %2" : "=v"(r) : "v"(a), "v"(b));
  return r;
}
__device__ __forceinline__ float plo(unsigned p) {
  union { unsigned u; float f; } v; v.u = p << 16; return v.f;
}
__device__ __forceinline__ float phi(unsigned p) {
  union { unsigned u; float f; } v; v.u = p & 0xffff0000u; return v.f;
}

__global__ __launch_bounds__(256) void prep_kernel(PrepArgs A) {
  const int mat = blockIdx.x;
  const float* __restrict__ src = A.src[mat];
  const int K = A.K[mat], N = A.N[mat], KS = K >> 5;
  ushort* dst = A.dst + A.ofs[mat];
  const int total = (N * K) >> 3;
  for (int gi = threadIdx.x; gi < total; gi += 256) {
    int t = gi / (64 * KS), r = gi - t * 64 * KS;
    int ks = r >> 6, lane = r & 63;
    int cc = lane & 15, gg = lane >> 4;
    int n = t * 16 + cc, k0 = ks * 32 + gg * 8;
    ushort v[8];
#pragma unroll
    for (int j = 0; j < 8; ++j) v[j] = f2b(src[(size_t)(k0 + j) * N + n]);
    *(uint4*)(dst + (size_t)gi * 8) = *(const uint4*)v;
  }
}

// combined W = (A @ B) * scale, packed directly to fragment-major
__global__ __launch_bounds__(256) void prep2_kernel(Prep2Args Z) {
  const int m = blockIdx.x;
  const float* __restrict__ A = Z.A[m];
  const float* __restrict__ B = Z.B[m];
  const int K = Z.K[m], N = Z.N[m], I = Z.inner[m], KS = K >> 5;
  const float sc = Z.scale[m];
  ushort* dst = Z.dst + Z.ofs[m];
  const int total = (N * K) >> 3;
  for (int gi = threadIdx.x; gi < total; gi += 256) {
    int t = gi / (64 * KS), r = gi - t * 64 * KS;
    int ks = r >> 6, lane = r & 63;
    int cc = lane & 15, gg = lane >> 4;
    int n = t * 16 + cc, k0 = ks * 32 + gg * 8;
    ushort v[8];
    for (int j = 0; j < 8; ++j) {
      float acc = 0.f;
      for (int u = 0; u < I; ++u)
        acc += A[(size_t)(k0 + j) * I + u] * B[(size_t)u * N + n];
      v[j] = f2b(acc * sc);
    }
    *(uint4*)(dst + (size_t)gi * 8) = *(const uint4*)v;
  }
}

template<int N>
__device__ __forceinline__ void lda(const ushort* __restrict__ wb, unsigned lofs, bf16x8* a) {
#pragma unroll
  for (int i = 0; i < N; ++i) a[i] = *(const bf16x8*)(wb + i * 512 + lofs);
}
template<int T, int KS>
__device__ __forceinline__ void mfm(const bf16x8* a, const bf16x8* bf, f32x4* out) {
#pragma unroll
  for (int t = 0; t < T; ++t) {
    f32x4 acc = (f32x4){0, 0, 0, 0};
#pragma unroll
    for (int ks = 0; ks < KS; ++ks)
      acc = __builtin_amdgcn_mfma_f32_16x16x32_bf16(a[t * KS + ks], bf[ks], acc, 0, 0, 0);
    out[t] = acc;
  }
}
template<int T, int KS>
__device__ __forceinline__ void mfmacc(const bf16x8* a, const bf16x8* bf, f32x4* out) {
#pragma unroll
  for (int t = 0; t < T; ++t)
#pragma unroll
    for (int ks = 0; ks < KS; ++ks)
      out[t] = __builtin_amdgcn_mfma_f32_16x16x32_bf16(a[t * KS + ks], bf[ks], out[t], 0, 0, 0);
}

__device__ __forceinline__ void put2(ushort* b, int cg, int col, const f32x4& d) {
  uint2 p; p.x = pk2(d[0], d[1]); p.y = pk2(d[2], d[3]);
  *(uint2*)(b + cg + col) = p;
}
__device__ __forceinline__ bf16x8 getf(const ushort* b, int cg, int col, int g) {
  return *(const bf16x8*)(b + cg + col + 8 * g);
}
__device__ __forceinline__ bf16x8 ldf8(const float* __restrict__ p) {
  float4 a = *(const float4*)p, b4 = *(const float4*)(p + 4);
  union { unsigned u[4]; bf16x8 v; } r;
  r.u[0] = pk2(a.x, a.y); r.u[1] = pk2(a.z, a.w);
  r.u[2] = pk2(b4.x, b4.y); r.u[3] = pk2(b4.z, b4.w);
  return r.v;
}
__device__ __forceinline__ f32x4 silu4(const f32x4& d) {
  f32x4 o;
#pragma unroll
  for (int r = 0; r < 4; ++r) { float z = d[r] * 0.125f; o[r] = BETA * z / (1.f + __expf(-z)); }
  return o;
}
__device__ __forceinline__ void vecwin(const float* __restrict__ p,
                                       float y0, float y1, float y2,
                                       bf16x8& dotf, bf16x8* xvf) {
  float v[24];
#pragma unroll
  for (int q = 0; q < 6; ++q) *(float4*)&v[4 * q] = *(const float4*)(p + 4 * q);
  float dj[8];
#pragma unroll
  for (int j = 0; j < 8; ++j)
    dj[j] = (v[3 * j] * y0 + v[3 * j + 1] * y1 + v[3 * j + 2] * y2) * RSQ3;
  union { unsigned u[4]; bf16x8 w; } t;
#pragma unroll
  for (int q = 0; q < 4; ++q) t.u[q] = pk2(dj[2 * q], dj[2 * q + 1]);
  dotf = t.w;
#pragma unroll
  for (int i = 0; i < 3; ++i) {
#pragma unroll
    for (int q = 0; q < 4; ++q) t.u[q] = pk2(v[6 * q + i], v[6 * q + 3 + i]);
    xvf[i] = t.w;
  }
}

// MLP3 -> 12 packed w-tiles, chunked 3-tile rotation
__device__ __forceinline__ void mlp3(const ushort* __restrict__ wb, unsigned lofs,
                                     const bf16x8* h2, uint2* Wp) {
  bf16x8 aa[6], ab[6];
  lda<6>(wb, lofs, aa);
  lda<6>(wb + 6 * 512, lofs, ab);
  f32x4 dw[3];
  mfm<3, 2>(aa, h2, dw);
  lda<6>(wb + 12 * 512, lofs, aa);
#pragma unroll
  for (int t = 0; t < 3; ++t) { Wp[t].x = pk2(dw[t][0]*0.125f, dw[t][1]*0.125f); Wp[t].y = pk2(dw[t][2]*0.125f, dw[t][3]*0.125f); }
  mfm<3, 2>(ab, h2, dw);
  lda<6>(wb + 18 * 512, lofs, ab);
#pragma unroll
  for (int t = 0; t < 3; ++t) { Wp[3+t].x = pk2(dw[t][0]*0.125f, dw[t][1]*0.125f); Wp[3+t].y = pk2(dw[t][2]*0.125f, dw[t][3]*0.125f); }
  mfm<3, 2>(aa, h2, dw);
#pragma unroll
  for (int t = 0; t < 3; ++t) { Wp[6+t].x = pk2(dw[t][0]*0.125f, dw[t][1]*0.125f); Wp[6+t].y = pk2(dw[t][2]*0.125f, dw[t][3]*0.125f); }
  mfm<3, 2>(ab, h2, dw);
#pragma unroll
  for (int t = 0; t < 3; ++t) { Wp[9+t].x = pk2(dw[t][0]*0.125f, dw[t][1]*0.125f); Wp[9+t].y = pk2(dw[t][2]*0.125f, dw[t][3]*0.125f); }
}

// TP + folded SL for one path. ACC=false: overwrite os/ov; true: accumulate.
template<bool ED, bool ACC>
__device__ __forceinline__ void tp_sl(
    const ushort* __restrict__ WF, ushort* bA, int cg, int g, unsigned lofs,
    const bf16x8* xsf, const bf16x8* dotf, const bf16x8* xvi,
    const uint2* Wp, float ys, float yv0, float yv1, float yv2,
    f32x4* os, f32x4 (*ov)[2]) {
  constexpr int KA = ED ? 2 : 4;
  constexpr int KB = ED ? 1 : 2;
  const float SA = ED ? RS64 : RS128;
  const float SB = ED ? RS32 : RS64;

  // s_a -> MSP[0..63]
  {
    bf16x8 a[4 * KA]; f32x4 d[4];
    lda<4 * KA>(WF + (ED ? O_ess : O_nss), lofs, a);
    mfm<4, KA>(a, xsf, d);
#pragma unroll
    for (int t = 0; t < 4; ++t) {
      f32x4 m;
      m[0] = d[t][0]*ys*SA*plo(Wp[t].x); m[1] = d[t][1]*ys*SA*phi(Wp[t].x);
      m[2] = d[t][2]*ys*SA*plo(Wp[t].y); m[3] = d[t][3]*ys*SA*phi(Wp[t].y);
      put2(bA, cg, MSP + 16 * t + 4 * g, m);
    }
  }
  // s_b -> MSP[64..127]
  {
    bf16x8 a[4 * KB]; f32x4 d[4];
    lda<4 * KB>(WF + (ED ? O_evv : O_nvv), lofs, a);
    mfm<4, KB>(a, dotf, d);
#pragma unroll
    for (int t = 0; t < 4; ++t) {
      f32x4 m;
      m[0] = d[t][0]*SB*plo(Wp[4+t].x); m[1] = d[t][1]*SB*phi(Wp[4+t].x);
      m[2] = d[t][2]*SB*plo(Wp[4+t].y); m[3] = d[t][3]*SB*phi(Wp[4+t].y);
      put2(bA, cg, MSP + 64 + 16 * t + 4 * g, m);
    }
  }
  FENCE();
  // read mpf early; prefetch folded-SL weights
  bf16x8 mpf[4];
#pragma unroll
  for (int ks = 0; ks < 4; ++ks) mpf[ks] = getf(bA, cg, MSP + 32 * ks, g);
  bf16x8 acs[16];
  lda<16>(WF + (ED ? O_ces : O_cns), lofs, acs);

  // v_a shared tiles + per-i v_b -> MV scratch -> folded SL-v accumulate
  f32x4 ga[2];
  {
    bf16x8 a[2 * KA];
    lda<2 * KA>(WF + (ED ? O_esv : O_nsv), lofs, a);
    mfm<2, KA>(a, xsf, ga);
  }
  bf16x8 avs[2 * KB];
  lda<2 * KB>(WF + (ED ? O_evs : O_nvs), lofs, avs);
  bf16x8 acv[4];
  lda<4>(WF + (ED ? O_cev : O_cnv), lofs, acv);
#pragma unroll
  for (int i = 0; i < 3; ++i) {
    f32x4 db[2];
    mfm<2, KB>(avs, xvi + i * KB, db);
    float yvi = (i == 0) ? yv0 : ((i == 1) ? yv1 : yv2);
#pragma unroll
    for (int t = 0; t < 2; ++t) {
      f32x4 m;
      m[0] = ga[t][0]*SA*yvi*plo(Wp[8+t].x); m[1] = ga[t][1]*SA*yvi*phi(Wp[8+t].x);
      m[2] = ga[t][2]*SA*yvi*plo(Wp[8+t].y); m[3] = ga[t][3]*SA*yvi*phi(Wp[8+t].y);
      put2(bA, cg, MV + 16 * t + 4 * g, m);
    }
#pragma unroll
    for (int t = 0; t < 2; ++t) {
      f32x4 m;
      m[0] = db[t][0]*ys*SB*plo(Wp[10+t].x); m[1] = db[t][1]*ys*SB*phi(Wp[10+t].x);
      m[2] = db[t][2]*ys*SB*plo(Wp[10+t].y); m[3] = db[t][3]*ys*SB*phi(Wp[10+t].y);
      put2(bA, cg, MV + 32 + 16 * t + 4 * g, m);
    }
    FENCE();
    bf16x8 mvf[2] = { getf(bA, cg, MV, g), getf(bA, cg, MV + 32, g) };
    if (ACC) mfmacc<2, 2>(acv, mvf, ov[i]);
    else     mfm<2, 2>(acv, mvf, ov[i]);
    FENCE();   // ov read-back done before next i overwrites MV
  }
  // folded SL-s accumulate (mpf long since read)
  if (ACC) mfmacc<4, 4>(acs, mpf, os);
  else     mfm<4, 4>(acs, mpf, os);
}

__global__ __launch_bounds__(256, 2) void mp_kernel(Ptrs P) {
  const int tid  = threadIdx.x;
  const int lane = tid & 63, wid = tid >> 6;
  const int c    = lane & 15, g  = lane >> 4;
  const unsigned lofs = lane * 8;
  const int cg   = c * ST;
  const int e    = (blockIdx.x * 4 + wid) * 16 + c;
  const ushort* __restrict__ WF = P.wf;

  __shared__ ushort sb[4][16][ST];
  ushort* bA = &sb[wid][0][0];

  const float* __restrict__ rs = P.src + (size_t)e * 160;
  const float* __restrict__ rd = P.dst + (size_t)e * 160;
  const float* __restrict__ re = P.ef  + (size_t)e * 160;
  const float* __restrict__ rq = P.scal + (size_t)e * 64;

  bf16x8 a1n[8], a1e[8];
  lda<8>(WF + O_nm1, lofs, a1n);
  lda<8>(WF + O_em1, lofs, a1e);

  float4 ev = *(const float4*)(P.env + (size_t)e * 4);
  const float ys = ev.x, yv0 = ev.y, yv1 = ev.z, yv2 = ev.w;
  bf16x8 sc[2];
  sc[0] = ldf8(rq + 8 * g);
  sc[1] = ldf8(rq + 32 + 8 * g);

  // ---- MLP1 (node+edge interleaved) ----
  {
    f32x4 dn[4], de[4];
    mfm<4, 2>(a1n, sc, dn); mfm<4, 2>(a1e, sc, de);
#pragma unroll
    for (int t = 0; t < 4; ++t) put2(bA, cg, H0n + 16 * t + 4 * g, silu4(dn[t]));
#pragma unroll
    for (int t = 0; t < 4; ++t) put2(bA, cg, H0e + 16 * t + 4 * g, silu4(de[t]));
  }
  FENCE();

  // ---- MLP2 + node TP input streams ----
  bf16x8 a2n[8], a2e[8];
  lda<8>(WF + O_nm2, lofs, a2n);
  lda<8>(WF + O_em2, lofs, a2e);
  bf16x8 xsf_n[4];
  xsf_n[0] = ldf8(rs + 8 * g);  xsf_n[1] = ldf8(rs + 32 + 8 * g);
  xsf_n[2] = ldf8(rd + 8 * g);  xsf_n[3] = ldf8(rd + 32 + 8 * g);
  bf16x8 dot_n[2], xv_n[6];
  {
    bf16x8 tmp[3];
    vecwin(rs + 64 + 24 * g, yv0, yv1, yv2, dot_n[0], tmp);
    xv_n[0] = tmp[0]; xv_n[2] = tmp[1]; xv_n[4] = tmp[2];
    vecwin(rd + 64 + 24 * g, yv0, yv1, yv2, dot_n[1], tmp);
    xv_n[1] = tmp[0]; xv_n[3] = tmp[1]; xv_n[5] = tmp[2];
  }
  {
    bf16x8 hn[2] = { getf(bA, cg, H0n, g), getf(bA, cg, H0n + 32, g) };
    bf16x8 he[2] = { getf(bA, cg, H0e, g), getf(bA, cg, H0e + 32, g) };
    f32x4 dn[4], de[4];
    mfm<4, 2>(a2n, hn, dn); mfm<4, 2>(a2e, he, de);
#pragma unroll
    for (int t = 0; t < 4; ++t) put2(bA, cg, H1n + 16 * t + 4 * g, silu4(dn[t]));
#pragma unroll
    for (int t = 0; t < 4; ++t) put2(bA, cg, H1e + 16 * t + 4 * g, silu4(de[t]));
  }
  FENCE();

  // ---- node MLP3 ----
  uint2 Wpn[12];
  {
    bf16x8 h2n[2] = { getf(bA, cg, H1n, g), getf(bA, cg, H1n + 32, g) };
    mlp3(WF + O_nm3, lofs, h2n, Wpn);
  }
  FENCE();   // H1n read complete before node TP overwrites MSP/MV

  // ---- node TP + folded SL (overwrite os/ov) ----
  f32x4 os[4]; f32x4 ov[3][2];
  tp_sl<false, false>(WF, bA, cg, g, lofs, xsf_n, dot_n, xv_n, Wpn, ys, yv0, yv1, yv2, os, ov);

  // ---- edge MLP3 (H1e still live at cols 192..255) + edge TP inputs ----
  bf16x8 xsf_e[2], dot_e[1], xv_e[3];
  xsf_e[0] = ldf8(re + 8 * g); xsf_e[1] = ldf8(re + 32 + 8 * g);
  {
    bf16x8 tmp[3];
    vecwin(re + 64 + 24 * g, yv0, yv1, yv2, dot_e[0], tmp);
    xv_e[0] = tmp[0]; xv_e[1] = tmp[1]; xv_e[2] = tmp[2];
  }
  uint2 Wpe[12];
  {
    bf16x8 h2e[2] = { getf(bA, cg, H1e, g), getf(bA, cg, H1e + 32, g) };
    mlp3(WF + O_em3, lofs, h2e, Wpe);
  }
  FENCE();

  // ---- edge TP + folded SL (accumulate) ----
  tp_sl<true, true>(WF, bA, cg, g, lofs, xsf_e, dot_e, xv_e, Wpe, ys, yv0, yv1, yv2, os, ov);

  // ---- store (scales baked into combined weights) ----
  float* __restrict__ po = P.out + (size_t)e * 160;
#pragma unroll
  for (int t = 0; t < 4; ++t) {
    float4 o = { os[t][0], os[t][1], os[t][2], os[t][3] };
    *(float4*)(po + 16 * t + 4 * g) = o;
  }
#pragma unroll
  for (int t = 0; t < 2; ++t) {
    float vv[12];
#pragma unroll
    for (int r = 0; r < 4; ++r)
#pragma unroll
      for (int i = 0; i < 3; ++i) vv[3 * r + i] = ov[i][t][r];
    *(float4*)(po + 64 + 48 * t + 12 * g)     = *(float4*)&vv[0];
    *(float4*)(po + 64 + 48 * t + 12 * g + 4) = *(float4*)&vv[4];
    *(float4*)(po + 64 + 48 * t + 12 * g + 8) = *(float4*)&vv[8];
  }
}

extern "C" void kernel_launch(void* const* d_in, const int* in_sizes, int n_in,
                              void* d_out, int out_size, void* d_ws, size_t ws_size,
                              hipStream_t stream) {
  PrepArgs A;
  const int src_idx[14] = {21,22,23, 24,25,26, 5,7,6,8, 9,11,10,12};
  const int Ks[14] = {64,64,64, 64,64,64, 128,128,64,64, 64,64,32,32};
  const int Ns[14] = {64,64,192, 64,64,192, 64,32,64,32, 64,32,64,32};
  const int Os[14] = {O_nm1,O_nm2,O_nm3, O_em1,O_em2,O_em3,
                      O_nss,O_nsv,O_nvv,O_nvs, O_ess,O_esv,O_evv,O_evs};
  for (int i = 0; i < 14; ++i) {
    A.src[i] = (const float*)d_in[src_idx[i]];
    A.K[i] = Ks[i]; A.N[i] = Ns[i]; A.ofs[i] = Os[i];
  }
  A.dst = (ushort*)d_ws;
  prep_kernel<<<dim3(14), dim3(256), 0, stream>>>(A);

  Prep2Args Z;
  // 0: node-s = Wns_s @ Wno_s ; 1: node-v = Wns_v @ Wno_v ; 2/3: edge
  Z.A[0] = (const float*)d_in[13]; Z.B[0] = (const float*)d_in[17];
  Z.K[0] = 128; Z.N[0] = 64; Z.inner[0] = 64; Z.ofs[0] = O_cns; Z.scale[0] = RS128 * RS64;
  Z.A[1] = (const float*)d_in[14]; Z.B[1] = (const float*)d_in[18];
  Z.K[1] = 64;  Z.N[1] = 32; Z.inner[1] = 32; Z.ofs[1] = O_cnv; Z.scale[1] = RS64 * RS32;
  Z.A[2] = (const float*)d_in[15]; Z.B[2] = (const float*)d_in[19];
  Z.K[2] = 128; Z.N[2] = 64; Z.inner[2] = 64; Z.ofs[2] = O_ces; Z.scale[2] = RS128 * RS64;
  Z.A[3] = (const float*)d_in[16]; Z.B[3] = (const float*)d_in[20];
  Z.K[3] = 64;  Z.N[3] = 32; Z.inner[3] = 32; Z.ofs[3] = O_cev; Z.scale[3] = RS64 * RS32;
  Z.dst = (ushort*)d_ws;
  prep2_kernel<<<dim3(4), dim3(256), 0, stream>>>(Z);

  Ptrs P;
  P.src  = (const float*)d_in[0];
  P.dst  = (const float*)d_in[1];
  P.ef   = (const float*)d_in[2];
  P.env  = (const float*)d_in[3];
  P.scal = (const float*)d_in[4];
  P.wf   = (const ushort*)d_ws;
  P.out  = (float*)d_out;

  const int E = in_sizes[0] / 160;  // 131072
  mp_kernel<<<dim3(E / 64), dim3(256), 0, stream>>>(P);
}

// Round 13
// 145.278 us; speedup vs baseline: 2.8686x; 2.1101x over previous
//
#include <hip/hip_runtime.h>

// R13: R12 with prep2 fixed: A/B staged in LDS (A transposed [I][K] to kill
// bank conflicts), grid 4x4=16 blocks, unrolled inner loop. mp_kernel and all
// layouts identical to R12 (passed, absmax 0.1875). Isolates mp's true cost.

typedef short  bf16x8 __attribute__((ext_vector_type(8)));
typedef float  f32x4  __attribute__((ext_vector_type(4)));

#define FENCE() asm volatile("" ::: "memory")

constexpr float BETA  = 1.6791767f;
constexpr float RS128 = 0.088388347648318447f;
constexpr float RS64  = 0.125f;
constexpr float RS32  = 0.176776695296636881f;
constexpr float RSQ3  = 0.577350269189625842f;

enum : int {
  O_nm1 = 0,      O_nm2 = 4096,   O_nm3 = 8192,
  O_em1 = 20480,  O_em2 = 24576,  O_em3 = 28672,
  O_nss = 40960,  O_nsv = 49152,  O_nvv = 53248,  O_nvs = 57344,
  O_ess = 59392,  O_esv = 63488,  O_evv = 65536,  O_evs = 67584,
  O_cns = 68608,  O_cnv = 76800,  O_ces = 78848,  O_cev = 87040,  // combined
  W_TOTAL = 89088
};

// arena column bases (per-wave [16][260] ushort)
enum : int { ST = 260, H0n = 0, H0e = 64, H1n = 128, H1e = 192, MSP = 0, MV = 128 };

struct Ptrs {
  const float *src, *dst, *ef, *env, *scal;
  const ushort* wf;
  float *out;
};

struct PrepArgs {
  const float* src[14];
  int K[14], N[14], ofs[14];
  ushort* dst;
};
struct Prep2Args {
  const float* A[4]; const float* B[4];
  int K[4], N[4], inner[4], ofs[4];
  float scale[4];
  ushort* dst;
};

__device__ __forceinline__ ushort f2b(float x) {
  union { float f; unsigned u; } v; v.f = x;
  unsigned r = v.u + 0x7fffu + ((v.u >> 16) & 1u);
  return (ushort)(r >> 16);
}
__device__ __forceinline__ unsigned pk2(float a, float b) {
  unsigned r;
  asm("v_cvt_pk_bf16_f32 %0, %1, %2" : "=v"(r) : "v"(a), "v"(b));
  return r;
}
__device__ __forceinline__ float plo(unsigned p) {
  union { unsigned u; float f; } v; v.u = p << 16; return v.f;
}
__device__ __forceinline__ float phi(unsigned p) {
  union { unsigned u; float f; } v; v.u = p & 0xffff0000u; return v.f;
}

__global__ __launch_bounds__(256) void prep_kernel(PrepArgs A) {
  const int mat = blockIdx.x;
  const float* __restrict__ src = A.src[mat];
  const int K = A.K[mat], N = A.N[mat], KS = K >> 5;
  ushort* dst = A.dst + A.ofs[mat];
  const int total = (N * K) >> 3;
  for (int gi = threadIdx.x; gi < total; gi += 256) {
    int t = gi / (64 * KS), r = gi - t * 64 * KS;
    int ks = r >> 6, lane = r & 63;
    int cc = lane & 15, gg = lane >> 4;
    int n = t * 16 + cc, k0 = ks * 32 + gg * 8;
    ushort v[8];
#pragma unroll
    for (int j = 0; j < 8; ++j) v[j] = f2b(src[(size_t)(k0 + j) * N + n]);
    *(uint4*)(dst + (size_t)gi * 8) = *(const uint4*)v;
  }
}

// combined W = (A @ B) * scale via LDS-staged operands, packed fragment-major.
// A staged TRANSPOSED as sAt[u][k] (stride K) so the j-unrolled reads are
// contiguous; B staged as-is. grid = (4 matrices) x (4 chunks).
__global__ __launch_bounds__(256) void prep2_kernel(Prep2Args Z) {
  const int m = blockIdx.x;
  const float* __restrict__ A = Z.A[m];
  const float* __restrict__ B = Z.B[m];
  const int K = Z.K[m], N = Z.N[m], I = Z.inner[m], KS = K >> 5;
  const float sc = Z.scale[m];
  ushort* dst = Z.dst + Z.ofs[m];

  __shared__ float sAt[8192];   // [I][K], max 64*128
  __shared__ float sB [4096];   // [I][N], max 64*64
  for (int idx = threadIdx.x; idx < K * I; idx += 256) {
    int k = idx / I, u = idx - k * I;
    sAt[u * K + k] = A[idx];
  }
  for (int idx = threadIdx.x; idx < I * N; idx += 256) sB[idx] = B[idx];
  __syncthreads();

  const int total = (N * K) >> 3;
  for (int gi = blockIdx.y * 256 + threadIdx.x; gi < total; gi += gridDim.y * 256) {
    int t = gi / (64 * KS), r = gi - t * 64 * KS;
    int ks = r >> 6, lane = r & 63;
    int cc = lane & 15, gg = lane >> 4;
    int n = t * 16 + cc, k0 = ks * 32 + gg * 8;
    float acc[8] = {0, 0, 0, 0, 0, 0, 0, 0};
    for (int u = 0; u < I; ++u) {
      float bv = sB[u * N + n];
      const float* ap = &sAt[u * K + k0];
#pragma unroll
      for (int j = 0; j < 8; ++j) acc[j] += ap[j] * bv;
    }
    ushort v[8];
#pragma unroll
    for (int j = 0; j < 8; ++j) v[j] = f2b(acc[j] * sc);
    *(uint4*)(dst + (size_t)gi * 8) = *(const uint4*)v;
  }
}

template<int N>
__device__ __forceinline__ void lda(const ushort* __restrict__ wb, unsigned lofs, bf16x8* a) {
#pragma unroll
  for (int i = 0; i < N; ++i) a[i] = *(const bf16x8*)(wb + i * 512 + lofs);
}
template<int T, int KS>
__device__ __forceinline__ void mfm(const bf16x8* a, const bf16x8* bf, f32x4* out) {
#pragma unroll
  for (int t = 0; t < T; ++t) {
    f32x4 acc = (f32x4){0, 0, 0, 0};
#pragma unroll
    for (int ks = 0; ks < KS; ++ks)
      acc = __builtin_amdgcn_mfma_f32_16x16x32_bf16(a[t * KS + ks], bf[ks], acc, 0, 0, 0);
    out[t] = acc;
  }
}
template<int T, int KS>
__device__ __forceinline__ void mfmacc(const bf16x8* a, const bf16x8* bf, f32x4* out) {
#pragma unroll
  for (int t = 0; t < T; ++t)
#pragma unroll
    for (int ks = 0; ks < KS; ++ks)
      out[t] = __builtin_amdgcn_mfma_f32_16x16x32_bf16(a[t * KS + ks], bf[ks], out[t], 0, 0, 0);
}

__device__ __forceinline__ void put2(ushort* b, int cg, int col, const f32x4& d) {
  uint2 p; p.x = pk2(d[0], d[1]); p.y = pk2(d[2], d[3]);
  *(uint2*)(b + cg + col) = p;
}
__device__ __forceinline__ bf16x8 getf(const ushort* b, int cg, int col, int g) {
  return *(const bf16x8*)(b + cg + col + 8 * g);
}
__device__ __forceinline__ bf16x8 ldf8(const float* __restrict__ p) {
  float4 a = *(const float4*)p, b4 = *(const float4*)(p + 4);
  union { unsigned u[4]; bf16x8 v; } r;
  r.u[0] = pk2(a.x, a.y); r.u[1] = pk2(a.z, a.w);
  r.u[2] = pk2(b4.x, b4.y); r.u[3] = pk2(b4.z, b4.w);
  return r.v;
}
__device__ __forceinline__ f32x4 silu4(const f32x4& d) {
  f32x4 o;
#pragma unroll
  for (int r = 0; r < 4; ++r) { float z = d[r] * 0.125f; o[r] = BETA * z / (1.f + __expf(-z)); }
  return o;
}
__device__ __forceinline__ void vecwin(const float* __restrict__ p,
                                       float y0, float y1, float y2,
                                       bf16x8& dotf, bf16x8* xvf) {
  float v[24];
#pragma unroll
  for (int q = 0; q < 6; ++q) *(float4*)&v[4 * q] = *(const float4*)(p + 4 * q);
  float dj[8];
#pragma unroll
  for (int j = 0; j < 8; ++j)
    dj[j] = (v[3 * j] * y0 + v[3 * j + 1] * y1 + v[3 * j + 2] * y2) * RSQ3;
  union { unsigned u[4]; bf16x8 w; } t;
#pragma unroll
  for (int q = 0; q < 4; ++q) t.u[q] = pk2(dj[2 * q], dj[2 * q + 1]);
  dotf = t.w;
#pragma unroll
  for (int i = 0; i < 3; ++i) {
#pragma unroll
    for (int q = 0; q < 4; ++q) t.u[q] = pk2(v[6 * q + i], v[6 * q + 3 + i]);
    xvf[i] = t.w;
  }
}

// MLP3 -> 12 packed w-tiles, chunked 3-tile rotation
__device__ __forceinline__ void mlp3(const ushort* __restrict__ wb, unsigned lofs,
                                     const bf16x8* h2, uint2* Wp) {
  bf16x8 aa[6], ab[6];
  lda<6>(wb, lofs, aa);
  lda<6>(wb + 6 * 512, lofs, ab);
  f32x4 dw[3];
  mfm<3, 2>(aa, h2, dw);
  lda<6>(wb + 12 * 512, lofs, aa);
#pragma unroll
  for (int t = 0; t < 3; ++t) { Wp[t].x = pk2(dw[t][0]*0.125f, dw[t][1]*0.125f); Wp[t].y = pk2(dw[t][2]*0.125f, dw[t][3]*0.125f); }
  mfm<3, 2>(ab, h2, dw);
  lda<6>(wb + 18 * 512, lofs, ab);
#pragma unroll
  for (int t = 0; t < 3; ++t) { Wp[3+t].x = pk2(dw[t][0]*0.125f, dw[t][1]*0.125f); Wp[3+t].y = pk2(dw[t][2]*0.125f, dw[t][3]*0.125f); }
  mfm<3, 2>(aa, h2, dw);
#pragma unroll
  for (int t = 0; t < 3; ++t) { Wp[6+t].x = pk2(dw[t][0]*0.125f, dw[t][1]*0.125f); Wp[6+t].y = pk2(dw[t][2]*0.125f, dw[t][3]*0.125f); }
  mfm<3, 2>(ab, h2, dw);
#pragma unroll
  for (int t = 0; t < 3; ++t) { Wp[9+t].x = pk2(dw[t][0]*0.125f, dw[t][1]*0.125f); Wp[9+t].y = pk2(dw[t][2]*0.125f, dw[t][3]*0.125f); }
}

// TP + folded SL for one path. ACC=false: overwrite os/ov; true: accumulate.
template<bool ED, bool ACC>
__device__ __forceinline__ void tp_sl(
    const ushort* __restrict__ WF, ushort* bA, int cg, int g, unsigned lofs,
    const bf16x8* xsf, const bf16x8* dotf, const bf16x8* xvi,
    const uint2* Wp, float ys, float yv0, float yv1, float yv2,
    f32x4* os, f32x4 (*ov)[2]) {
  constexpr int KA = ED ? 2 : 4;
  constexpr int KB = ED ? 1 : 2;
  const float SA = ED ? RS64 : RS128;
  const float SB = ED ? RS32 : RS64;

  // s_a -> MSP[0..63]
  {
    bf16x8 a[4 * KA]; f32x4 d[4];
    lda<4 * KA>(WF + (ED ? O_ess : O_nss), lofs, a);
    mfm<4, KA>(a, xsf, d);
#pragma unroll
    for (int t = 0; t < 4; ++t) {
      f32x4 m;
      m[0] = d[t][0]*ys*SA*plo(Wp[t].x); m[1] = d[t][1]*ys*SA*phi(Wp[t].x);
      m[2] = d[t][2]*ys*SA*plo(Wp[t].y); m[3] = d[t][3]*ys*SA*phi(Wp[t].y);
      put2(bA, cg, MSP + 16 * t + 4 * g, m);
    }
  }
  // s_b -> MSP[64..127]
  {
    bf16x8 a[4 * KB]; f32x4 d[4];
    lda<4 * KB>(WF + (ED ? O_evv : O_nvv), lofs, a);
    mfm<4, KB>(a, dotf, d);
#pragma unroll
    for (int t = 0; t < 4; ++t) {
      f32x4 m;
      m[0] = d[t][0]*SB*plo(Wp[4+t].x); m[1] = d[t][1]*SB*phi(Wp[4+t].x);
      m[2] = d[t][2]*SB*plo(Wp[4+t].y); m[3] = d[t][3]*SB*phi(Wp[4+t].y);
      put2(bA, cg, MSP + 64 + 16 * t + 4 * g, m);
    }
  }
  FENCE();
  // read mpf early; prefetch folded-SL weights
  bf16x8 mpf[4];
#pragma unroll
  for (int ks = 0; ks < 4; ++ks) mpf[ks] = getf(bA, cg, MSP + 32 * ks, g);
  bf16x8 acs[16];
  lda<16>(WF + (ED ? O_ces : O_cns), lofs, acs);

  // v_a shared tiles + per-i v_b -> MV scratch -> folded SL-v accumulate
  f32x4 ga[2];
  {
    bf16x8 a[2 * KA];
    lda<2 * KA>(WF + (ED ? O_esv : O_nsv), lofs, a);
    mfm<2, KA>(a, xsf, ga);
  }
  bf16x8 avs[2 * KB];
  lda<2 * KB>(WF + (ED ? O_evs : O_nvs), lofs, avs);
  bf16x8 acv[4];
  lda<4>(WF + (ED ? O_cev : O_cnv), lofs, acv);
#pragma unroll
  for (int i = 0; i < 3; ++i) {
    f32x4 db[2];
    mfm<2, KB>(avs, xvi + i * KB, db);
    float yvi = (i == 0) ? yv0 : ((i == 1) ? yv1 : yv2);
#pragma unroll
    for (int t = 0; t < 2; ++t) {
      f32x4 m;
      m[0] = ga[t][0]*SA*yvi*plo(Wp[8+t].x); m[1] = ga[t][1]*SA*yvi*phi(Wp[8+t].x);
      m[2] = ga[t][2]*SA*yvi*plo(Wp[8+t].y); m[3] = ga[t][3]*SA*yvi*phi(Wp[8+t].y);
      put2(bA, cg, MV + 16 * t + 4 * g, m);
    }
#pragma unroll
    for (int t = 0; t < 2; ++t) {
      f32x4 m;
      m[0] = db[t][0]*ys*SB*plo(Wp[10+t].x); m[1] = db[t][1]*ys*SB*phi(Wp[10+t].x);
      m[2] = db[t][2]*ys*SB*plo(Wp[10+t].y); m[3] = db[t][3]*ys*SB*phi(Wp[10+t].y);
      put2(bA, cg, MV + 32 + 16 * t + 4 * g, m);
    }
    FENCE();
    bf16x8 mvf[2] = { getf(bA, cg, MV, g), getf(bA, cg, MV + 32, g) };
    if (ACC) mfmacc<2, 2>(acv, mvf, ov[i]);
    else     mfm<2, 2>(acv, mvf, ov[i]);
    FENCE();   // ov read-back done before next i overwrites MV
  }
  // folded SL-s accumulate (mpf long since read)
  if (ACC) mfmacc<4, 4>(acs, mpf, os);
  else     mfm<4, 4>(acs, mpf, os);
}

__global__ __launch_bounds__(256, 2) void mp_kernel(Ptrs P) {
  const int tid  = threadIdx.x;
  const int lane = tid & 63, wid = tid >> 6;
  const int c    = lane & 15, g  = lane >> 4;
  const unsigned lofs = lane * 8;
  const int cg   = c * ST;
  const int e    = (blockIdx.x * 4 + wid) * 16 + c;
  const ushort* __restrict__ WF = P.wf;

  __shared__ ushort sb[4][16][ST];
  ushort* bA = &sb[wid][0][0];

  const float* __restrict__ rs = P.src + (size_t)e * 160;
  const float* __restrict__ rd = P.dst + (size_t)e * 160;
  const float* __restrict__ re = P.ef  + (size_t)e * 160;
  const float* __restrict__ rq = P.scal + (size_t)e * 64;

  bf16x8 a1n[8], a1e[8];
  lda<8>(WF + O_nm1, lofs, a1n);
  lda<8>(WF + O_em1, lofs, a1e);

  float4 ev = *(const float4*)(P.env + (size_t)e * 4);
  const float ys = ev.x, yv0 = ev.y, yv1 = ev.z, yv2 = ev.w;
  bf16x8 sc[2];
  sc[0] = ldf8(rq + 8 * g);
  sc[1] = ldf8(rq + 32 + 8 * g);

  // ---- MLP1 (node+edge interleaved) ----
  {
    f32x4 dn[4], de[4];
    mfm<4, 2>(a1n, sc, dn); mfm<4, 2>(a1e, sc, de);
#pragma unroll
    for (int t = 0; t < 4; ++t) put2(bA, cg, H0n + 16 * t + 4 * g, silu4(dn[t]));
#pragma unroll
    for (int t = 0; t < 4; ++t) put2(bA, cg, H0e + 16 * t + 4 * g, silu4(de[t]));
  }
  FENCE();

  // ---- MLP2 + node TP input streams ----
  bf16x8 a2n[8], a2e[8];
  lda<8>(WF + O_nm2, lofs, a2n);
  lda<8>(WF + O_em2, lofs, a2e);
  bf16x8 xsf_n[4];
  xsf_n[0] = ldf8(rs + 8 * g);  xsf_n[1] = ldf8(rs + 32 + 8 * g);
  xsf_n[2] = ldf8(rd + 8 * g);  xsf_n[3] = ldf8(rd + 32 + 8 * g);
  bf16x8 dot_n[2], xv_n[6];
  {
    bf16x8 tmp[3];
    vecwin(rs + 64 + 24 * g, yv0, yv1, yv2, dot_n[0], tmp);
    xv_n[0] = tmp[0]; xv_n[2] = tmp[1]; xv_n[4] = tmp[2];
    vecwin(rd + 64 + 24 * g, yv0, yv1, yv2, dot_n[1], tmp);
    xv_n[1] = tmp[0]; xv_n[3] = tmp[1]; xv_n[5] = tmp[2];
  }
  {
    bf16x8 hn[2] = { getf(bA, cg, H0n, g), getf(bA, cg, H0n + 32, g) };
    bf16x8 he[2] = { getf(bA, cg, H0e, g), getf(bA, cg, H0e + 32, g) };
    f32x4 dn[4], de[4];
    mfm<4, 2>(a2n, hn, dn); mfm<4, 2>(a2e, he, de);
#pragma unroll
    for (int t = 0; t < 4; ++t) put2(bA, cg, H1n + 16 * t + 4 * g, silu4(dn[t]));
#pragma unroll
    for (int t = 0; t < 4; ++t) put2(bA, cg, H1e + 16 * t + 4 * g, silu4(de[t]));
  }
  FENCE();

  // ---- node MLP3 ----
  uint2 Wpn[12];
  {
    bf16x8 h2n[2] = { getf(bA, cg, H1n, g), getf(bA, cg, H1n + 32, g) };
    mlp3(WF + O_nm3, lofs, h2n, Wpn);
  }
  FENCE();   // H1n read complete before node TP overwrites MSP/MV

  // ---- node TP + folded SL (overwrite os/ov) ----
  f32x4 os[4]; f32x4 ov[3][2];
  tp_sl<false, false>(WF, bA, cg, g, lofs, xsf_n, dot_n, xv_n, Wpn, ys, yv0, yv1, yv2, os, ov);

  // ---- edge MLP3 (H1e still live at cols 192..255) + edge TP inputs ----
  bf16x8 xsf_e[2], dot_e[1], xv_e[3];
  xsf_e[0] = ldf8(re + 8 * g); xsf_e[1] = ldf8(re + 32 + 8 * g);
  {
    bf16x8 tmp[3];
    vecwin(re + 64 + 24 * g, yv0, yv1, yv2, dot_e[0], tmp);
    xv_e[0] = tmp[0]; xv_e[1] = tmp[1]; xv_e[2] = tmp[2];
  }
  uint2 Wpe[12];
  {
    bf16x8 h2e[2] = { getf(bA, cg, H1e, g), getf(bA, cg, H1e + 32, g) };
    mlp3(WF + O_em3, lofs, h2e, Wpe);
  }
  FENCE();

  // ---- edge TP + folded SL (accumulate) ----
  tp_sl<true, true>(WF, bA, cg, g, lofs, xsf_e, dot_e, xv_e, Wpe, ys, yv0, yv1, yv2, os, ov);

  // ---- store (scales baked into combined weights) ----
  float* __restrict__ po = P.out + (size_t)e * 160;
#pragma unroll
  for (int t = 0; t < 4; ++t) {
    float4 o = { os[t][0], os[t][1], os[t][2], os[t][3] };
    *(float4*)(po + 16 * t + 4 * g) = o;
  }
#pragma unroll
  for (int t = 0; t < 2; ++t) {
    float vv[12];
#pragma unroll
    for (int r = 0; r < 4; ++r)
#pragma unroll
      for (int i = 0; i < 3; ++i) vv[3 * r + i] = ov[i][t][r];
    *(float4*)(po + 64 + 48 * t + 12 * g)     = *(float4*)&vv[0];
    *(float4*)(po + 64 + 48 * t + 12 * g + 4) = *(float4*)&vv[4];
    *(float4*)(po + 64 + 48 * t + 12 * g + 8) = *(float4*)&vv[8];
  }
}

extern "C" void kernel_launch(void* const* d_in, const int* in_sizes, int n_in,
                              void* d_out, int out_size, void* d_ws, size_t ws_size,
                              hipStream_t stream) {
  PrepArgs A;
  const int src_idx[14] = {21,22,23, 24,25,26, 5,7,6,8, 9,11,10,12};
  const int Ks[14] = {64,64,64, 64,64,64, 128,128,64,64, 64,64,32,32};
  const int Ns[14] = {64,64,192, 64,64,192, 64,32,64,32, 64,32,64,32};
  const int Os[14] = {O_nm1,O_nm2,O_nm3, O_em1,O_em2,O_em3,
                      O_nss,O_nsv,O_nvv,O_nvs, O_ess,O_esv,O_evv,O_evs};
  for (int i = 0; i < 14; ++i) {
    A.src[i] = (const float*)d_in[src_idx[i]];
    A.K[i] = Ks[i]; A.N[i] = Ns[i]; A.ofs[i] = Os[i];
  }
  A.dst = (ushort*)d_ws;
  prep_kernel<<<dim3(14), dim3(256), 0, stream>>>(A);

  Prep2Args Z;
  // 0: node-s = Wns_s @ Wno_s ; 1: node-v = Wns_v @ Wno_v ; 2/3: edge
  Z.A[0] = (const float*)d_in[13]; Z.B[0] = (const float*)d_in[17];
  Z.K[0] = 128; Z.N[0] = 64; Z.inner[0] = 64; Z.ofs[0] = O_cns; Z.scale[0] = RS128 * RS64;
  Z.A[1] = (const float*)d_in[14]; Z.B[1] = (const float*)d_in[18];
  Z.K[1] = 64;  Z.N[1] = 32; Z.inner[1] = 32; Z.ofs[1] = O_cnv; Z.scale[1] = RS64 * RS32;
  Z.A[2] = (const float*)d_in[15]; Z.B[2] = (const float*)d_in[19];
  Z.K[2] = 128; Z.N[2] = 64; Z.inner[2] = 64; Z.ofs[2] = O_ces; Z.scale[2] = RS128 * RS64;
  Z.A[3] = (const float*)d_in[16]; Z.B[3] = (const float*)d_in[20];
  Z.K[3] = 64;  Z.N[3] = 32; Z.inner[3] = 32; Z.ofs[3] = O_cev; Z.scale[3] = RS64 * RS32;
  Z.dst = (ushort*)d_ws;
  prep2_kernel<<<dim3(4, 4), dim3(256), 0, stream>>>(Z);

  Ptrs P;
  P.src  = (const float*)d_in[0];
  P.dst  = (const float*)d_in[1];
  P.ef   = (const float*)d_in[2];
  P.env  = (const float*)d_in[3];
  P.scal = (const float*)d_in[4];
  P.wf   = (const ushort*)d_ws;
  P.out  = (float*)d_out;

  const int E = in_sizes[0] / 160;  // 131072
  mp_kernel<<<dim3(E / 64), dim3(256), 0, stream>>>(P);
}